// Round 4
// baseline (664.124 us; speedup 1.0000x reference)
//
#include <hip/hip_runtime.h>
#include <hip/hip_bf16.h>
#include <cstdint>

#define DIM 1024
#define BATCH 4
#define SEQ 8192
#define M_TOTAL (BATCH * SEQ)   // 32768

#define CH 64               // chunks per sequence for the scan
#define CL (SEQ / CH)       // chunk length = 128

using bf16 = __hip_bfloat16;
typedef __attribute__((ext_vector_type(4))) float f32x4;
typedef __attribute__((ext_vector_type(8))) __bf16 bf16x8;

#define NI 8                // 8 outer iterations x 2 K-tiles (BK=64) = K=1024

// Template-faithful sync idioms: builtin barrier, BARE waitcnt asm (no
// "memory" clobber -> no compiler-forced vmcnt(0) drain; round-1 lesson).
#define BAR()      __builtin_amdgcn_s_barrier()
#define LGKM0()    asm volatile("s_waitcnt lgkmcnt(0)")
#define WAIT_VM(n) asm volatile("s_waitcnt vmcnt(" #n ")")
// asm-pinned 16B global load / LDS write (mutually ordered volatile asm).
#define GLOAD(D, P) asm volatile("global_load_dwordx4 %0, %1, off" : "=v"(D) : "v"(P))
#define DSW(A, V)   asm volatile("ds_write_b128 %0, %1" :: "v"(A), "v"(V))

// ---------------------------------------------------------------------------
// fp32 -> bf16 conversion for the two weight matrices only (x handled in
// GEMM1 staging now).
// ---------------------------------------------------------------------------
__global__ void convert_w(const float* __restrict__ w1, bf16* __restrict__ o1,
                          const float* __restrict__ w2, bf16* __restrict__ o2) {
    const long n4 = (long)DIM * DIM / 4;
    long i = blockIdx.x * 256L + threadIdx.x;
    const float* in; bf16* out; long off;
    if (i < n4) { in = w1; out = o1; off = i; }
    else        { in = w2; out = o2; off = i - n4; }
    const float4 v = ((const float4*)in)[off];
    __hip_bfloat162* o = (__hip_bfloat162*)(out + off * 4);
    o[0] = __float22bfloat162_rn(make_float2(v.x, v.y));
    o[1] = __float22bfloat162_rn(make_float2(v.z, v.w));
}

// ---------------------------------------------------------------------------
// B-operand staging: one half-tile (128 rows x 64 cols bf16 = 16KB) via
// global_load_lds, XOR swizzle kcs = kc ^ (row&7) applied by pre-swizzling
// the GLOBAL source (LDS dest linear).
// ---------------------------------------------------------------------------
__device__ __forceinline__ void stage_half(const bf16* __restrict__ g,
                                           char* ldsbase, int tid) {
    const int w = tid >> 6, l = tid & 63;
    const int kc = (l & 7) ^ ((l >> 3) & 7);
#pragma unroll
    for (int j = 0; j < 2; j++) {
        const int idx = (w * 2 + j) * 64 + l;
        const int row = w * 16 + j * 8 + (l >> 3);
        const bf16* src = g + (size_t)row * DIM + kc * 8;
        __builtin_amdgcn_global_load_lds(
            (const __attribute__((address_space(1))) void*)src,
            (__attribute__((address_space(3))) void*)(ldsbase + idx * 16),
            16, 0, 0);
    }
}

// pack 8 f32 -> 8 bf16 (returned as f32x4 bit-pattern for asm operands)
__device__ __forceinline__ f32x4 cvt8(f32x4 a, f32x4 b) {
    bf16x8 r;
#pragma unroll
    for (int i = 0; i < 4; i++) { r[i] = (__bf16)a[i]; r[4 + i] = (__bf16)b[i]; }
    return __builtin_bit_cast(f32x4, r);
}
// y(bf16x8) + p*c elementwise -> bf16x8 (scan carry fix)
__device__ __forceinline__ f32x4 fix8(f32x4 yv, f32x4 plo, f32x4 phi,
                                      f32x4 clo, f32x4 chi) {
    bf16x8 y = __builtin_bit_cast(bf16x8, yv);
    bf16x8 r;
#pragma unroll
    for (int i = 0; i < 4; i++) {
        r[i]     = (__bf16)((float)y[i]     + plo[i] * clo[i]);
        r[4 + i] = (__bf16)((float)y[4 + i] + phi[i] * chi[i]);
    }
    return __builtin_bit_cast(f32x4, r);
}

// ---------------------------------------------------------------------------
// 256x256 8-phase GEMM, C = A * B^T + bias. 512 thr = 8 waves (2M x 4N),
// mfma_f32_16x16x32_bf16, BK=64, 2 K-tiles/iter, counted vmcnt (never 0 in
// steady state). A-operand is REG-STAGED (asm loads -> vmcnt(N) with reg
// deps -> asm ds_write), B via global_load_lds.
// MODE 1: A = x fp32 (cvt to bf16); out bf16 ylocal + fused chunk scan -> S.
// MODE 2: A = ylocal bf16 with y = ylocal + powA*carry fix; out fp32.
//   (K-dimension of A in MODE2 IS the channel axis d: powA/carry pointers
//    must carry the +KT channel offset — round-3 bug.)
// vmcnt invariants (La = A-loads/thread/half: MODE1 4, MODE2 8):
//  iter start: 4 outstanding (B(t+1) gll). ph1:+La ph2:+La
//  ph3: vmcnt(La) [prevB+A0 done] writeA0, +2 gll B0(t+2)
//  ph4: vmcnt(2)  [A1 done]       writeA1, +2 gll B1(t+2)
//  ph5:+La ph6:+La
//  ph7: vmcnt(La) [B(t+2)+A0' done] writeA0', +2 gll B0(t+3)
//  ph8: vmcnt(2)  [A1' done]        writeA1', +2 gll B1(t+3) -> 4 ✓
// ---------------------------------------------------------------------------
template <int MODE>
__global__ __launch_bounds__(512, 2) void gemm256(
    const void* __restrict__ Asrc, const bf16* __restrict__ B,
    const float* __restrict__ bias, void* __restrict__ C,
    const float* __restrict__ acoef, const float* __restrict__ bcoef,
    float* __restrict__ S, const float* __restrict__ powA,
    const float* __restrict__ carry) {
    __shared__ __align__(16) char lds[131072];

    const float* Xf = (const float*)Asrc;
    const bf16*  Yb = (const bf16*)Asrc;

    const int tid  = threadIdx.x;
    const int wave = tid >> 6;
    const int l    = tid & 63;

    // XCD-aware bijective swizzle: 512 blocks = 8 xcd x (16 bm x 4 bn).
    const int orig = blockIdx.x;
    const int xcd  = orig & 7;
    const int li   = orig >> 3;
    const int bm   = xcd * 16 + (li >> 2);   // 0..127
    const int bn   = li & 3;                 // 0..3

    const bf16* Bbase = B + (size_t)bn * 256 * DIM;

    char* pa0 = lds + (wave >> 2) * 16384;
    char* pb0 = lds + 32768 + ((wave & 3) >> 1) * 16384 + (wave & 1) * 8192;
    char* pa1 = pa0 + 65536;
    char* pb1 = pb0 + 65536;

    const int rl = l & 15;
    const int lg = l >> 4;
    const int r7 = l & 7;
    const int ao0 = rl * 128 + ((lg ^ r7) << 4);
    const int ao1 = rl * 128 + (((4 + lg) ^ r7) << 4);

    // A reg-stage lane constants (natural kc; swizzle applied at ds_write)
    const int kcn  = l & 7;
    const int r8   = l >> 3;             // 0..7
    const int slot = kcn ^ r8;
    const int rA0  = wave * 16 + r8;     // local row, j=0 (j=1 -> +8)
    const int colA = kcn * 8;
    const unsigned ldsb32 =
        (unsigned)(uintptr_t)(__attribute__((address_space(3))) char*)lds;
    const unsigned dsoff0 = (unsigned)(rA0 * 128 + slot * 16);
    const unsigned dsoff1 = dsoff0 + 1024;

    // staging registers (two slots: at most 2 halves in flight)
    f32x4 xa00a, xa00b, xa01a, xa01b, xa10a, xa10b, xa11a, xa11b;   // MODE1
    f32x4 ya00, ya01, ya10, ya11;                                    // MODE2
    f32x4 pa00a, pa00b, pa01a, pa01b, pa10a, pa10b, pa11a, pa11b;
    f32x4 ca0a, ca0b, ca1a, ca1b;

#define A_ISSUE(Sl, KT, RH) do {                                              \
    if constexpr (MODE == 1) {                                                \
        const float* p_ = Xf + ((size_t)(bm * 256 + (RH) * 128 + rA0)) * DIM  \
                          + (KT) + colA;                                      \
        GLOAD(xa##Sl##0a, p_);           GLOAD(xa##Sl##0b, p_ + 4);           \
        GLOAD(xa##Sl##1a, p_ + 8 * DIM); GLOAD(xa##Sl##1b, p_ + 8 * DIM + 4); \
    } else {                                                                  \
        const bf16* y_ = Yb + ((size_t)(bm * 256 + (RH) * 128 + rA0)) * DIM   \
                         + (KT) + colA;                                       \
        const float* pw_ = powA + (size_t)rA0 * DIM + (KT) + colA;            \
        const float* cw_ = carry + (size_t)(bm * 2 + (RH)) * DIM + (KT) + colA; \
        GLOAD(ya##Sl##0, y_); GLOAD(ya##Sl##1, y_ + 8 * DIM);                 \
        GLOAD(pa##Sl##0a, pw_);           GLOAD(pa##Sl##0b, pw_ + 4);         \
        GLOAD(pa##Sl##1a, pw_ + 8 * DIM); GLOAD(pa##Sl##1b, pw_ + 8 * DIM + 4); \
        GLOAD(ca##Sl##a, cw_);            GLOAD(ca##Sl##b, cw_ + 4);          \
    } } while (0)

#define A_WW(Sl, N1, N2, DSB) do {                                            \
    if constexpr (MODE == 1) {                                                \
        asm volatile("s_waitcnt vmcnt(" N1 ")"                                \
            : "+v"(xa##Sl##0a), "+v"(xa##Sl##0b),                             \
              "+v"(xa##Sl##1a), "+v"(xa##Sl##1b));                            \
        f32x4 t0_ = cvt8(xa##Sl##0a, xa##Sl##0b);                             \
        f32x4 t1_ = cvt8(xa##Sl##1a, xa##Sl##1b);                             \
        DSW(ldsb32 + (DSB) + dsoff0, t0_);                                    \
        DSW(ldsb32 + (DSB) + dsoff1, t1_);                                    \
    } else {                                                                  \
        asm volatile("s_waitcnt vmcnt(" N2 ")"                                \
            : "+v"(ya##Sl##0), "+v"(ya##Sl##1),                               \
              "+v"(pa##Sl##0a), "+v"(pa##Sl##0b),                             \
              "+v"(pa##Sl##1a), "+v"(pa##Sl##1b),                             \
              "+v"(ca##Sl##a), "+v"(ca##Sl##b));                              \
        f32x4 t0_ = fix8(ya##Sl##0, pa##Sl##0a, pa##Sl##0b, ca##Sl##a, ca##Sl##b); \
        f32x4 t1_ = fix8(ya##Sl##1, pa##Sl##1a, pa##Sl##1b, ca##Sl##a, ca##Sl##b); \
        DSW(ldsb32 + (DSB) + dsoff0, t0_);                                    \
        DSW(ldsb32 + (DSB) + dsoff1, t1_);                                    \
    } } while (0)

    f32x4 acc[8][4];
#pragma unroll
    for (int m = 0; m < 8; m++)
#pragma unroll
        for (int n = 0; n < 4; n++)
#pragma unroll
            for (int r = 0; r < 4; r++) acc[m][n][r] = 0.f;

    bf16x8 af[4][2], bfr[4][2];

#define READ_A4(PA, FMB)                                                   \
    _Pragma("unroll") for (int m_ = 0; m_ < 4; m_++) {                     \
        af[m_][0] = *(const bf16x8*)((PA) + (FMB + m_) * 2048 + ao0);      \
        af[m_][1] = *(const bf16x8*)((PA) + (FMB + m_) * 2048 + ao1);      \
    }
#define READ_B2(PB, FNB)                                                   \
    _Pragma("unroll") for (int n_ = 0; n_ < 2; n_++) {                     \
        bfr[FNB + n_][0] = *(const bf16x8*)((PB) + (FNB + n_) * 2048 + ao0); \
        bfr[FNB + n_][1] = *(const bf16x8*)((PB) + (FNB + n_) * 2048 + ao1); \
    }
#define MFMA16(MB, NB2)                                                    \
    __builtin_amdgcn_s_setprio(1);                                         \
    _Pragma("unroll") for (int m_ = 0; m_ < 4; m_++)                       \
    _Pragma("unroll") for (int n_ = 0; n_ < 2; n_++)                       \
    _Pragma("unroll") for (int k_ = 0; k_ < 2; k_++)                       \
        acc[MB + m_][NB2 + n_] = __builtin_amdgcn_mfma_f32_16x16x32_bf16(  \
            af[m_][k_], bfr[NB2 + n_][k_], acc[MB + m_][NB2 + n_], 0, 0, 0); \
    __builtin_amdgcn_s_setprio(0);

    // Prologue: A(tile0) reg-issue; B(tile0)+B(tile1) gll; write A(tile0).
    A_ISSUE(0, 0, 0);
    A_ISSUE(1, 0, 1);
    stage_half(Bbase,                          lds + 32768, tid);
    stage_half(Bbase + (size_t)128 * DIM,      lds + 49152, tid);
    stage_half(Bbase + 64,                     lds + 65536 + 32768, tid);
    stage_half(Bbase + (size_t)128 * DIM + 64, lds + 65536 + 49152, tid);
    A_WW(0, "8", "8", 0);
    A_WW(1, "8", "8", 16384);
    LGKM0();
    WAIT_VM(4);      // B(tile0) landed; B(tile1) 4 ops in flight = invariant
    BAR();

    for (int i = 0; i < NI; ++i) {
        const bool last = (i == NI - 1);
        const int kt1 = (2 * i + 1) * 64;
        const int kt2 = kt1 + 64;
        const int kt3 = kt1 + 128;

        // ---- window 0: K-tile t from buf0 ----
        READ_A4(pa0, 0); READ_B2(pb0, 0);                       // ph1
        A_ISSUE(0, kt1, 0);
        BAR(); LGKM0(); MFMA16(0, 0); BAR();

        READ_B2(pb0, 2);                                        // ph2
        A_ISSUE(1, kt1, 1);
        BAR(); LGKM0(); MFMA16(0, 2); BAR();

        READ_A4(pa0, 4);                                        // ph3
        A_WW(0, "4", "8", 65536);
        if (!last) stage_half(Bbase + kt2, lds + 32768, tid);
        LGKM0(); BAR(); MFMA16(4, 0); BAR();

        if (!last) {                                            // ph4
            A_WW(1, "2", "2", 65536 + 16384);
            stage_half(Bbase + (size_t)128 * DIM + kt2, lds + 49152, tid);
        } else {
            A_WW(1, "0", "0", 65536 + 16384);
        }
        LGKM0(); BAR(); MFMA16(4, 2); BAR();

        // ---- window 1: K-tile t+1 from buf1 ----
        READ_A4(pa1, 0); READ_B2(pb1, 0);                       // ph5
        if (!last) A_ISSUE(0, kt2, 0);
        BAR(); LGKM0(); MFMA16(0, 0); BAR();

        READ_B2(pb1, 2);                                        // ph6
        if (!last) A_ISSUE(1, kt2, 1);
        BAR(); LGKM0(); MFMA16(0, 2); BAR();

        READ_A4(pa1, 4);                                        // ph7
        if (!last) {
            A_WW(0, "4", "8", 0);
            stage_half(Bbase + kt3, lds + 65536 + 32768, tid);
        }
        LGKM0(); BAR(); MFMA16(4, 0); BAR();

        if (!last) {                                            // ph8
            A_WW(1, "2", "2", 16384);
            stage_half(Bbase + (size_t)128 * DIM + kt3, lds + 65536 + 49152, tid);
        }
        LGKM0(); BAR(); MFMA16(4, 2); BAR();
    }

    // Epilogue. 16x16 C/D layout: col = lane&15, row = (lane>>4)*4 + reg.
    const int wm = (wave >> 2) * 128;
    const int wn = (wave & 3) * 64;
    const long mb = (long)bm * 256 + wm;
    const int nb = bn * 256 + wn;
    const int crow = lg * 4;

    float bv[4];
#pragma unroll
    for (int n = 0; n < 4; n++) bv[n] = bias[nb + n * 16 + rl];

    if constexpr (MODE == 2) {
        float* O = (float*)C;
#pragma unroll
        for (int m = 0; m < 8; m++)
#pragma unroll
            for (int n = 0; n < 4; n++) {
                const int col = nb + n * 16 + rl;
#pragma unroll
                for (int r = 0; r < 4; r++)
                    O[(mb + m * 16 + crow + r) * (long)DIM + col] =
                        acc[m][n][r] + bv[n];
            }
    } else {
        // Stash h-tile in LDS (dead after main loop), run the chunk-local
        // scan, store ylocal (every step) + S (final). Tile rows 256 =
        // exactly 2 chunks (CL=128). Swizzle cb = (col*2) ^ ((row>>2&7)<<4).
        for (int m = 0; m < 8; m++)
#pragma unroll
            for (int n = 0; n < 4; n++) {
                const int lcol = wn + n * 16 + rl;
#pragma unroll
                for (int r = 0; r < 4; r++) {
                    const int lrow = wm + m * 16 + crow + r;
                    const bf16 hv = __float2bfloat16(acc[m][n][r] + bv[n]);
                    const int cb = (lcol * 2) ^ (((lrow >> 2) & 7) << 4);
                    *(bf16*)(lds + lrow * 512 + cb) = hv;
                }
            }
        __syncthreads();
        const int c   = tid & 255;
        const int ch2 = tid >> 8;
        const int d   = bn * 256 + c;
        const float Ad = 1.f / (1.f + expf(-acoef[d]));
        const float bd = bcoef[d];
        bf16* Yo = (bf16*)C;
        const size_t rbase = (size_t)bm * 256 + (size_t)ch2 * 128;
        float s = 0.f;
#pragma unroll 8
        for (int t = 0; t < CL; t++) {
            const int lrow = ch2 * 128 + t;
            const int cb = (c * 2) ^ (((lrow >> 2) & 7) << 4);
            const float v =
                __bfloat162float(*(const bf16*)(lds + lrow * 512 + cb));
            s = Ad * s + bd * v;
            Yo[(rbase + t) * DIM + d] = __float2bfloat16(s);
        }
        S[((size_t)bm * 2 + ch2) * DIM + d] = s;
    }
#undef A_ISSUE
#undef A_WW
#undef READ_A4
#undef READ_B2
#undef MFMA16
}

// ---------------------------------------------------------------------------
// carry[g][d] = incoming chunk state (chain over 64 chunks per batch, using
// Ap = A^128); powA[t][d] = A^(t+1) for t=0..127.
// ---------------------------------------------------------------------------
__global__ __launch_bounds__(512) void carry_powA(
    const float* __restrict__ a, const float* __restrict__ S,
    float* __restrict__ carry, float* __restrict__ powA) {
    if (blockIdx.x < 8) {
        const int idx = blockIdx.x * 512 + threadIdx.x;  // b*1024 + d
        const int b = idx >> 10, d = idx & 1023;
        const float A = 1.f / (1.f + expf(-a[d]));
        float Ap = A;
#pragma unroll
        for (int i = 0; i < 7; i++) Ap *= Ap;            // A^128
        float acc = 0.f;
        for (int c = 0; c < CH; c++) {
            const size_t g = (size_t)b * CH + c;
            carry[g * DIM + d] = acc;
            acc = Ap * acc + S[g * DIM + d];
        }
    } else {
        const int d = (blockIdx.x - 8) * 512 + threadIdx.x;
        if (d < DIM) {
            const float A = 1.f / (1.f + expf(-a[d]));
            float p = A;
            for (int k = 0; k < CL; k++) {
                powA[(size_t)k * DIM + d] = p;
                p *= A;
            }
        }
    }
}

// ---------------------------------------------------------------------------
extern "C" void kernel_launch(void* const* d_in, const int* in_sizes, int n_in,
                              void* d_out, int out_size, void* d_ws,
                              size_t ws_size, hipStream_t stream) {
    const float* x     = (const float*)d_in[0];
    const float* w_in  = (const float*)d_in[1];
    const float* b_in  = (const float*)d_in[2];
    const float* a     = (const float*)d_in[3];
    const float* bcoef = (const float*)d_in[4];
    const float* w_out = (const float*)d_in[5];
    const float* b_out = (const float*)d_in[6];
    float* out = (float*)d_out;

    char* ws = (char*)d_ws;
    bf16*  wib   = (bf16*)ws;  ws += (size_t)DIM * DIM * 2;          // 2 MB
    bf16*  wob   = (bf16*)ws;  ws += (size_t)DIM * DIM * 2;          // 2 MB
    bf16*  Ybuf  = (bf16*)ws;  ws += (size_t)M_TOTAL * DIM * 2;      // 64 MB
    float* S     = (float*)ws; ws += (size_t)BATCH * CH * DIM * 4;   // 1 MB
    float* carry = (float*)ws; ws += (size_t)BATCH * CH * DIM * 4;   // 1 MB
    float* powA  = (float*)ws; ws += (size_t)CL * DIM * 4;           // 512 KB

    // 1. weights fp32 -> bf16 (x no longer converted: GEMM1 reads fp32)
    convert_w<<<2048, 256, 0, stream>>>(w_in, wib, w_out, wob);

    const int nblocks = (M_TOTAL / 256) * (DIM / 256);  // 512

    // 2. h = x @ w_in^T + b_in; fused chunk-local scan -> ylocal (bf16) + S
    gemm256<1><<<nblocks, 512, 0, stream>>>(x, wib, b_in, Ybuf, a, bcoef, S,
                                            nullptr, nullptr);

    // 3. chunk carries + A-power table (tiny, L2-resident)
    carry_powA<<<10, 512, 0, stream>>>(a, S, carry, powA);

    // 4. out = (ylocal + powA*carry) @ w_out^T + b_out  (fix fused in staging)
    gemm256<2><<<nblocks, 512, 0, stream>>>(Ybuf, wob, b_out, out, nullptr,
                                            nullptr, nullptr, powA, carry);
}